// Round 4
// baseline (500.572 us; speedup 1.0000x reference)
//
#include <hip/hip_runtime.h>
#include <math.h>

#define D_DIM 16
#define N_PTS 100
#define VMIN_F (-5.0f)
#define INT_LEN_F (10.0f / 99.0f)
#define INV_INT_LEN_F (99.0f / 10.0f)
#define UF 4

// ---------------------------------------------------------------------------
// Setup kernel (1 block, 256 threads) — unchanged from round 0 (verified):
//  - Gauss-Jordan inverse of (I - A) in fp64 (partial pivoting) -> Minv [16x16]
//  - Combined PWL table Ctab[d][idx] = { w(idx), delta_bias(max(idx-1,0)) }
// ---------------------------------------------------------------------------
__global__ void scm_setup(const float* __restrict__ A,
                          const float* __restrict__ p,
                          const float* __restrict__ b,
                          float* __restrict__ Minv,
                          float2* __restrict__ Ctab) {
    __shared__ double aug[16][33];   // [I-A | I], padded
    __shared__ float db_s[16][N_PTS];
    __shared__ int piv;
    const int t = threadIdx.x;

    if (t < 16) {
        #pragma unroll
        for (int j = 0; j < 16; j++) {
            aug[t][j]      = (t == j ? 1.0 : 0.0) - (double)A[t * 16 + j];
            aug[t][16 + j] = (t == j ? 1.0 : 0.0);
        }
    }
    __syncthreads();

    for (int k = 0; k < 16; k++) {
        if (t == 0) {
            int pr = k; double best = fabs(aug[k][k]);
            for (int i = k + 1; i < 16; i++) {
                double v = fabs(aug[i][k]);
                if (v > best) { best = v; pr = i; }
            }
            piv = pr;
        }
        __syncthreads();
        const int pr = piv;
        if (pr != k && t < 32) {
            double tmp = aug[k][t]; aug[k][t] = aug[pr][t]; aug[pr][t] = tmp;
        }
        __syncthreads();
        const double pivval = aug[k][k];
        __syncthreads();
        if (t < 32) aug[k][t] = aug[k][t] / pivval;
        __syncthreads();
        if (t < 16 && t != k) {
            const double f = aug[t][k];
            #pragma unroll
            for (int j = 0; j < 32; j++) aug[t][j] -= f * aug[k][j];
        }
        __syncthreads();
    }

    if (t < 16) {
        #pragma unroll
        for (int j = 0; j < 16; j++) Minv[t * 16 + j] = (float)aug[t][16 + j];
    }

    // serial per-dim fp32 cumsum (matches reference jnp.cumsum ordering)
    if (t < 16) {
        float acc = b[t];
        db_s[t][0] = acc;
        for (int i = 1; i < N_PTS; i++) {
            acc += INT_LEN_F * (expf(p[t * (N_PTS + 1) + i]) + 0.001f);
            db_s[t][i] = acc;
        }
    }
    __syncthreads();

    // combined table: one float2 per (d, idx)
    for (int i = t; i < 16 * (N_PTS + 1); i += blockDim.x) {
        const int d   = i / (N_PTS + 1);
        const int idx = i - d * (N_PTS + 1);
        const int spi = idx > 0 ? idx - 1 : 0;
        float2 c;
        c.x = expf(p[i]) + 0.001f;   // w at idx
        c.y = db_s[d][spi];          // delta_bias at sp_idx
        Ctab[i] = c;
    }
}

// DPP quad_perm broadcast: every lane in an aligned quad receives lane J's x.
// Pure VALU (no LDS pipe). Quads are always fully active together (total is a
// multiple of 4 and per-element guards are quad-aligned).
template <int J>
__device__ __forceinline__ float dpp_bcast(float x) {
    constexpr int ctrl = J | (J << 2) | (J << 4) | (J << 6);  // quad_perm
    int xi = __builtin_bit_cast(int, x);
    int r  = __builtin_amdgcn_mov_dpp(xi, ctrl, 0xf, 0xf, true);
    return __builtin_bit_cast(float, r);
}

// ---------------------------------------------------------------------------
// Main kernel, v3 (BISECT: v2 structure, nt-store REVERTED):
//  Round-3 post-mortem: v2 (UF=4 + LDS-Minv + nt stores) exploded HBM traffic
//  6x (FETCH 62.6->677 MB, WRITE 125->457 MB). WRITE inflation ~3.65x matches
//  nt stores defeating TCC write-combining (per-lane 16B sectors instead of
//  full 128B lines); fetch >input-size indicates cache churn from the same.
//  This version keeps the latency fixes (which DID raise BW 2.36->3.7 TB/s):
//  * UF=4 grid-stride unroll, 4-deep prefetch (4 KB in flight per wave)
//  * Minv in LDS (1 KB), k-outer/u-inner (one ds_read_b128 per k, reused x4)
//  and restores the round-0 plain float4 store (proven 125 MB write traffic).
// ---------------------------------------------------------------------------
__global__ __launch_bounds__(256, 4) void scm_main(
        const float* __restrict__ eps,
        const float* __restrict__ Minv,
        const float2* __restrict__ Ctab,
        float* __restrict__ out, int B) {
    __shared__ float2 sC[16 * (N_PTS + 1)];   // 12928 B
    __shared__ float4 sM[64];                 // 1024 B; sM[k*4+q] = Minv[k][4q..4q+3]

    const int t = threadIdx.x;
    const int q = t & 3;                      // quarter within row

    for (int i = t; i < 16 * (N_PTS + 1); i += 256) sC[i] = Ctab[i];
    ((float*)sM)[t] = Minv[t];                // flat copy == desired layout
    __syncthreads();

    const float4* sMq = sM + q;               // sMq[4*k] = Minv[k][4q..4q+3]

    const int total  = B * 4;                 // float4 count (8M, fits int)
    const int stride = (int)gridDim.x * 256;
    const int sstep  = stride * UF;
    int base = (int)blockIdx.x * 256 + t;

    const float4* in4  = (const float4*)eps;
    float4*       out4 = (float4*)out;

    float4 cur[UF];
    #pragma unroll
    for (int u = 0; u < UF; u++) {
        const int idx = base + u * stride;
        cur[u] = (idx < total) ? in4[idx] : make_float4(0.f, 0.f, 0.f, 0.f);
    }

    for (; base < total; base += sstep) {
        // prefetch next super-group (4 loads in flight across this iteration)
        const int nbase = base + sstep;
        float4 nxt[UF];
        #pragma unroll
        for (int u = 0; u < UF; u++) {
            const int idx = nbase + u * stride;
            nxt[u] = (idx < total) ? in4[idx] : make_float4(0.f, 0.f, 0.f, 0.f);
        }

        float4 z0 = make_float4(0.f, 0.f, 0.f, 0.f);
        float4 z1 = make_float4(0.f, 0.f, 0.f, 0.f);
        float4 z2 = make_float4(0.f, 0.f, 0.f, 0.f);
        float4 z3 = make_float4(0.f, 0.f, 0.f, 0.f);

        // k-outer / u-inner: one LDS read of Minv row-quarter per k, reused
        // by all 4 rows; 16 independent FMA chains (4 z-vectors x 4 comps).
        // e[k = 4*G + C] = dpp_bcast<G>(component C of cur[u]).
#define SCM_STEP(G, C, COMP)                                                   \
        {                                                                      \
            const float4 mk = sMq[4 * (4 * (G) + (C))];                        \
            const float e0 = dpp_bcast<(G)>(cur[0].COMP);                      \
            const float e1 = dpp_bcast<(G)>(cur[1].COMP);                      \
            const float e2 = dpp_bcast<(G)>(cur[2].COMP);                      \
            const float e3 = dpp_bcast<(G)>(cur[3].COMP);                      \
            z0.x = fmaf(e0, mk.x, z0.x); z0.y = fmaf(e0, mk.y, z0.y);          \
            z0.z = fmaf(e0, mk.z, z0.z); z0.w = fmaf(e0, mk.w, z0.w);          \
            z1.x = fmaf(e1, mk.x, z1.x); z1.y = fmaf(e1, mk.y, z1.y);          \
            z1.z = fmaf(e1, mk.z, z1.z); z1.w = fmaf(e1, mk.w, z1.w);          \
            z2.x = fmaf(e2, mk.x, z2.x); z2.y = fmaf(e2, mk.y, z2.y);          \
            z2.z = fmaf(e2, mk.z, z2.z); z2.w = fmaf(e2, mk.w, z2.w);          \
            z3.x = fmaf(e3, mk.x, z3.x); z3.y = fmaf(e3, mk.y, z3.y);          \
            z3.z = fmaf(e3, mk.z, z3.z); z3.w = fmaf(e3, mk.w, z3.w);          \
        }
        SCM_STEP(0, 0, x) SCM_STEP(0, 1, y) SCM_STEP(0, 2, z) SCM_STEP(0, 3, w)
        SCM_STEP(1, 0, x) SCM_STEP(1, 1, y) SCM_STEP(1, 2, z) SCM_STEP(1, 3, w)
        SCM_STEP(2, 0, x) SCM_STEP(2, 1, y) SCM_STEP(2, 2, z) SCM_STEP(2, 3, w)
        SCM_STEP(3, 0, x) SCM_STEP(3, 1, y) SCM_STEP(3, 2, z) SCM_STEP(3, 3, w)
#undef SCM_STEP

        // PWL + store per row (uniform grid; continuous at knots)
        float4 zarr[UF] = {z0, z1, z2, z3};
        #pragma unroll
        for (int u = 0; u < UF; u++) {
            const int idx = base + u * stride;
            const float zv[4] = {zarr[u].x, zarr[u].y, zarr[u].z, zarr[u].w};
            float o[4];
            #pragma unroll
            for (int i = 0; i < 4; i++) {
                const float zd = zv[i];
                const float tt = (zd - VMIN_F) * INV_INT_LEN_F;
                int id = (int)floorf(tt) + 1;
                id = min(max(id, 0), N_PTS);
                const int sp_idx = max(id - 1, 0);
                const float sp = VMIN_F + (float)sp_idx * INT_LEN_F;
                const float2 c = sC[(4 * q + i) * (N_PTS + 1) + id];
                o[i] = fmaf(zd - sp, c.x, c.y);
            }
            if (idx < total) {
                out4[idx] = make_float4(o[0], o[1], o[2], o[3]);  // plain store
            }
        }

        #pragma unroll
        for (int u = 0; u < UF; u++) cur[u] = nxt[u];
    }
}

extern "C" void kernel_launch(void* const* d_in, const int* in_sizes, int n_in,
                              void* d_out, int out_size, void* d_ws, size_t ws_size,
                              hipStream_t stream) {
    const float* eps = (const float*)d_in[0];
    const float* A   = (const float*)d_in[1];
    const float* p   = (const float*)d_in[2];
    const float* b   = (const float*)d_in[3];
    float* out = (float*)d_out;

    const int B = in_sizes[0] / D_DIM;

    // workspace layout: Minv[256 floats] | Ctab[16*101 float2] (8B-aligned)
    float*  ws   = (float*)d_ws;
    float*  Minv = ws;
    float2* Ctab = (float2*)(ws + 256);

    scm_setup<<<1, 256, 0, stream>>>(A, p, b, Minv, Ctab);

    long total_f4 = (long)B * 4;
    int blocks = (int)((total_f4 + 255) / 256);
    if (blocks > 2048) blocks = 2048;
    if (blocks < 1) blocks = 1;
    scm_main<<<blocks, 256, 0, stream>>>(eps, Minv, Ctab, out, B);
}

// Round 5
// 273.239 us; speedup vs baseline: 1.8320x; 1.8320x over previous
//
#include <hip/hip_runtime.h>
#include <math.h>

#define D_DIM 16
#define N_PTS 100
#define VMIN_F (-5.0f)
#define INT_LEN_F (10.0f / 99.0f)
#define INV_INT_LEN_F (99.0f / 10.0f)

// ---------------------------------------------------------------------------
// Setup kernel (1 block, 256 threads) — unchanged from round 0 (verified):
//  - Gauss-Jordan inverse of (I - A) in fp64 (partial pivoting) -> Minv [16x16]
//  - Combined PWL table Ctab[d][idx] = { w(idx), delta_bias(max(idx-1,0)) }
// ---------------------------------------------------------------------------
__global__ void scm_setup(const float* __restrict__ A,
                          const float* __restrict__ p,
                          const float* __restrict__ b,
                          float* __restrict__ Minv,
                          float2* __restrict__ Ctab) {
    __shared__ double aug[16][33];   // [I-A | I], padded
    __shared__ float db_s[16][N_PTS];
    __shared__ int piv;
    const int t = threadIdx.x;

    if (t < 16) {
        #pragma unroll
        for (int j = 0; j < 16; j++) {
            aug[t][j]      = (t == j ? 1.0 : 0.0) - (double)A[t * 16 + j];
            aug[t][16 + j] = (t == j ? 1.0 : 0.0);
        }
    }
    __syncthreads();

    for (int k = 0; k < 16; k++) {
        if (t == 0) {
            int pr = k; double best = fabs(aug[k][k]);
            for (int i = k + 1; i < 16; i++) {
                double v = fabs(aug[i][k]);
                if (v > best) { best = v; pr = i; }
            }
            piv = pr;
        }
        __syncthreads();
        const int pr = piv;
        if (pr != k && t < 32) {
            double tmp = aug[k][t]; aug[k][t] = aug[pr][t]; aug[pr][t] = tmp;
        }
        __syncthreads();
        const double pivval = aug[k][k];
        __syncthreads();
        if (t < 32) aug[k][t] = aug[k][t] / pivval;
        __syncthreads();
        if (t < 16 && t != k) {
            const double f = aug[t][k];
            #pragma unroll
            for (int j = 0; j < 32; j++) aug[t][j] -= f * aug[k][j];
        }
        __syncthreads();
    }

    if (t < 16) {
        #pragma unroll
        for (int j = 0; j < 16; j++) Minv[t * 16 + j] = (float)aug[t][16 + j];
    }

    // serial per-dim fp32 cumsum (matches reference jnp.cumsum ordering)
    if (t < 16) {
        float acc = b[t];
        db_s[t][0] = acc;
        for (int i = 1; i < N_PTS; i++) {
            acc += INT_LEN_F * (expf(p[t * (N_PTS + 1) + i]) + 0.001f);
            db_s[t][i] = acc;
        }
    }
    __syncthreads();

    // combined table: one float2 per (d, idx)
    for (int i = t; i < 16 * (N_PTS + 1); i += blockDim.x) {
        const int d   = i / (N_PTS + 1);
        const int idx = i - d * (N_PTS + 1);
        const int spi = idx > 0 ? idx - 1 : 0;
        float2 c;
        c.x = expf(p[i]) + 0.001f;   // w at idx
        c.y = db_s[d][spi];          // delta_bias at sp_idx
        Ctab[i] = c;
    }
}

// DPP quad_perm broadcast: every lane in an aligned quad receives lane J's x.
// Pure VALU (no LDS pipe). Quads are always fully active together.
template <int J>
__device__ __forceinline__ float dpp_bcast(float x) {
    constexpr int ctrl = J | (J << 2) | (J << 4) | (J << 6);  // quad_perm
    int xi = __builtin_bit_cast(int, x);
    int r  = __builtin_amdgcn_mov_dpp(xi, ctrl, 0xf, 0xf, true);
    return __builtin_bit_cast(float, r);
}

// ---------------------------------------------------------------------------
// Main kernel, v4 (spill-proof 2-deep pipeline):
//  Round 3/4 post-mortem: UF=4 with float4 ARRAYS caused ~900 MB of scratch
//  spill/fill HBM traffic (FETCH 682 MB > input 128 MB; WRITE 460 vs 125 MB;
//  extra-read ~= extra-write; VGPR_Count pinned at exactly 64 = the
//  8-waves/EU tier). The allocator targeted the 64-reg tier and spilled the
//  ~80-reg live set. nt-store was exonerated by the round-4 bisect (identical
//  counters with plain stores).
//  v4: UF=2 with NAMED float4 scalars only (no indexable arrays -> nothing
//  the allocator can demote to scratch; live set ~50 VGPRs fits the 64 tier).
//  Keeps: Minv in LDS (k-outer, one ds_read_b128 per k amortized over both
//  rows), 2-deep cross-iteration prefetch, plain coalesced float4 stores.
// ---------------------------------------------------------------------------
__global__ __launch_bounds__(256, 4) void scm_main(
        const float* __restrict__ eps,
        const float* __restrict__ Minv,
        const float2* __restrict__ Ctab,
        float* __restrict__ out, int B) {
    __shared__ float2 sC[16 * (N_PTS + 1)];   // 12928 B
    __shared__ float4 sM[64];                 // 1024 B; sM[k*4+q] = Minv[k][4q..4q+3]

    const int t = threadIdx.x;
    const int q = t & 3;                      // quarter within row

    for (int i = t; i < 16 * (N_PTS + 1); i += 256) sC[i] = Ctab[i];
    ((float*)sM)[t] = Minv[t];                // flat copy == desired layout
    __syncthreads();

    const float4* sMq = sM + q;               // sMq[4*k] = Minv[k][4q..4q+3]

    const int total  = B * 4;                 // float4 count (8M, fits int)
    const int stride = (int)gridDim.x * 256;
    const int sstep  = stride * 2;            // two rows per iteration
    int base = (int)blockIdx.x * 256 + t;

    const float4* in4  = (const float4*)eps;
    float4*       out4 = (float4*)out;

    const float4 zero4 = make_float4(0.f, 0.f, 0.f, 0.f);

    float4 curA = (base < total)          ? in4[base]          : zero4;
    float4 curB = (base + stride < total) ? in4[base + stride] : zero4;

    for (; base < total; base += sstep) {
        // prefetch next pair (2 loads in flight across this iteration's compute)
        const int nb = base + sstep;
        float4 nxtA = (nb < total)          ? in4[nb]          : zero4;
        float4 nxtB = (nb + stride < total) ? in4[nb + stride] : zero4;

        float4 zA = zero4;
        float4 zB = zero4;

        // k-outer: one ds_read_b128 of the Minv row-quarter per k, reused by
        // both rows; 8 independent FMA chains. e[k=4G+C] = dpp_bcast<G>(comp C).
#define SCM_STEP(G, C, COMP)                                                   \
        {                                                                      \
            const float4 mk = sMq[4 * (4 * (G) + (C))];                        \
            const float eA = dpp_bcast<(G)>(curA.COMP);                        \
            const float eB = dpp_bcast<(G)>(curB.COMP);                        \
            zA.x = fmaf(eA, mk.x, zA.x); zA.y = fmaf(eA, mk.y, zA.y);          \
            zA.z = fmaf(eA, mk.z, zA.z); zA.w = fmaf(eA, mk.w, zA.w);          \
            zB.x = fmaf(eB, mk.x, zB.x); zB.y = fmaf(eB, mk.y, zB.y);          \
            zB.z = fmaf(eB, mk.z, zB.z); zB.w = fmaf(eB, mk.w, zB.w);          \
        }
        SCM_STEP(0, 0, x) SCM_STEP(0, 1, y) SCM_STEP(0, 2, z) SCM_STEP(0, 3, w)
        SCM_STEP(1, 0, x) SCM_STEP(1, 1, y) SCM_STEP(1, 2, z) SCM_STEP(1, 3, w)
        SCM_STEP(2, 0, x) SCM_STEP(2, 1, y) SCM_STEP(2, 2, z) SCM_STEP(2, 3, w)
        SCM_STEP(3, 0, x) SCM_STEP(3, 1, y) SCM_STEP(3, 2, z) SCM_STEP(3, 3, w)
#undef SCM_STEP

        // PWL + store, row A then row B (all scalars, no arrays)
#define SCM_PWL_STORE(ZV, IDX)                                                 \
        if ((IDX) < total) {                                                   \
            float o0, o1, o2, o3;                                              \
            {                                                                  \
                const float zd = (ZV).x;                                       \
                int id = (int)floorf((zd - VMIN_F) * INV_INT_LEN_F) + 1;       \
                id = min(max(id, 0), N_PTS);                                   \
                const int spi = max(id - 1, 0);                                \
                const float sp = VMIN_F + (float)spi * INT_LEN_F;              \
                const float2 c = sC[(4 * q + 0) * (N_PTS + 1) + id];           \
                o0 = fmaf(zd - sp, c.x, c.y);                                  \
            }                                                                  \
            {                                                                  \
                const float zd = (ZV).y;                                       \
                int id = (int)floorf((zd - VMIN_F) * INV_INT_LEN_F) + 1;       \
                id = min(max(id, 0), N_PTS);                                   \
                const int spi = max(id - 1, 0);                                \
                const float sp = VMIN_F + (float)spi * INT_LEN_F;              \
                const float2 c = sC[(4 * q + 1) * (N_PTS + 1) + id];           \
                o1 = fmaf(zd - sp, c.x, c.y);                                  \
            }                                                                  \
            {                                                                  \
                const float zd = (ZV).z;                                       \
                int id = (int)floorf((zd - VMIN_F) * INV_INT_LEN_F) + 1;       \
                id = min(max(id, 0), N_PTS);                                   \
                const int spi = max(id - 1, 0);                                \
                const float sp = VMIN_F + (float)spi * INT_LEN_F;              \
                const float2 c = sC[(4 * q + 2) * (N_PTS + 1) + id];           \
                o2 = fmaf(zd - sp, c.x, c.y);                                  \
            }                                                                  \
            {                                                                  \
                const float zd = (ZV).w;                                       \
                int id = (int)floorf((zd - VMIN_F) * INV_INT_LEN_F) + 1;       \
                id = min(max(id, 0), N_PTS);                                   \
                const int spi = max(id - 1, 0);                                \
                const float sp = VMIN_F + (float)spi * INT_LEN_F;              \
                const float2 c = sC[(4 * q + 3) * (N_PTS + 1) + id];           \
                o3 = fmaf(zd - sp, c.x, c.y);                                  \
            }                                                                  \
            out4[(IDX)] = make_float4(o0, o1, o2, o3);                         \
        }

        SCM_PWL_STORE(zA, base)
        SCM_PWL_STORE(zB, base + stride)
#undef SCM_PWL_STORE

        curA = nxtA;
        curB = nxtB;
    }
}

extern "C" void kernel_launch(void* const* d_in, const int* in_sizes, int n_in,
                              void* d_out, int out_size, void* d_ws, size_t ws_size,
                              hipStream_t stream) {
    const float* eps = (const float*)d_in[0];
    const float* A   = (const float*)d_in[1];
    const float* p   = (const float*)d_in[2];
    const float* b   = (const float*)d_in[3];
    float* out = (float*)d_out;

    const int B = in_sizes[0] / D_DIM;

    // workspace layout: Minv[256 floats] | Ctab[16*101 float2] (8B-aligned)
    float*  ws   = (float*)d_ws;
    float*  Minv = ws;
    float2* Ctab = (float2*)(ws + 256);

    scm_setup<<<1, 256, 0, stream>>>(A, p, b, Minv, Ctab);

    long total_f4 = (long)B * 4;
    int blocks = (int)((total_f4 + 255) / 256);
    if (blocks > 2048) blocks = 2048;
    if (blocks < 1) blocks = 1;
    scm_main<<<blocks, 256, 0, stream>>>(eps, Minv, Ctab, out, B);
}

// Round 6
// 269.964 us; speedup vs baseline: 1.8542x; 1.0121x over previous
//
#include <hip/hip_runtime.h>
#include <math.h>

#define D_DIM 16
#define N_PTS 100
#define VMIN_F (-5.0f)
#define INT_LEN_F (10.0f / 99.0f)
#define INV_INT_LEN_F (99.0f / 10.0f)

// clang ext-vector type: REQUIRED for __builtin_nontemporal_* — HIP's float4
// (HIP_vector_type struct) is rejected by the builtins (round-2 lesson).
typedef float f32x4_t __attribute__((ext_vector_type(4)));

// Nontemporal input load: do NOT allocate in L2/L3. Input is streamed once per
// dispatch; keeping it out of the LLC frees the full 256 MB for the write
// stream (round-5 theory: L3 at exact capacity input+output caps write drain
// at ~1.55 TB/s, which predicts dur in all 4 measured rounds).
__device__ __forceinline__ float4 nt_load4(const float4* p) {
    f32x4_t v = __builtin_nontemporal_load((const f32x4_t*)p);
    return make_float4(v.x, v.y, v.z, v.w);
}

// ---------------------------------------------------------------------------
// Setup kernel (1 block, 256 threads) — unchanged (verified):
//  - Gauss-Jordan inverse of (I - A) in fp64 (partial pivoting) -> Minv [16x16]
//  - Combined PWL table Ctab[d][idx] = { w(idx), delta_bias(max(idx-1,0)) }
// ---------------------------------------------------------------------------
__global__ void scm_setup(const float* __restrict__ A,
                          const float* __restrict__ p,
                          const float* __restrict__ b,
                          float* __restrict__ Minv,
                          float2* __restrict__ Ctab) {
    __shared__ double aug[16][33];   // [I-A | I], padded
    __shared__ float db_s[16][N_PTS];
    __shared__ int piv;
    const int t = threadIdx.x;

    if (t < 16) {
        #pragma unroll
        for (int j = 0; j < 16; j++) {
            aug[t][j]      = (t == j ? 1.0 : 0.0) - (double)A[t * 16 + j];
            aug[t][16 + j] = (t == j ? 1.0 : 0.0);
        }
    }
    __syncthreads();

    for (int k = 0; k < 16; k++) {
        if (t == 0) {
            int pr = k; double best = fabs(aug[k][k]);
            for (int i = k + 1; i < 16; i++) {
                double v = fabs(aug[i][k]);
                if (v > best) { best = v; pr = i; }
            }
            piv = pr;
        }
        __syncthreads();
        const int pr = piv;
        if (pr != k && t < 32) {
            double tmp = aug[k][t]; aug[k][t] = aug[pr][t]; aug[pr][t] = tmp;
        }
        __syncthreads();
        const double pivval = aug[k][k];
        __syncthreads();
        if (t < 32) aug[k][t] = aug[k][t] / pivval;
        __syncthreads();
        if (t < 16 && t != k) {
            const double f = aug[t][k];
            #pragma unroll
            for (int j = 0; j < 32; j++) aug[t][j] -= f * aug[k][j];
        }
        __syncthreads();
    }

    if (t < 16) {
        #pragma unroll
        for (int j = 0; j < 16; j++) Minv[t * 16 + j] = (float)aug[t][16 + j];
    }

    // serial per-dim fp32 cumsum (matches reference jnp.cumsum ordering)
    if (t < 16) {
        float acc = b[t];
        db_s[t][0] = acc;
        for (int i = 1; i < N_PTS; i++) {
            acc += INT_LEN_F * (expf(p[t * (N_PTS + 1) + i]) + 0.001f);
            db_s[t][i] = acc;
        }
    }
    __syncthreads();

    // combined table: one float2 per (d, idx)
    for (int i = t; i < 16 * (N_PTS + 1); i += blockDim.x) {
        const int d   = i / (N_PTS + 1);
        const int idx = i - d * (N_PTS + 1);
        const int spi = idx > 0 ? idx - 1 : 0;
        float2 c;
        c.x = expf(p[i]) + 0.001f;   // w at idx
        c.y = db_s[d][spi];          // delta_bias at sp_idx
        Ctab[i] = c;
    }
}

// DPP quad_perm broadcast: every lane in an aligned quad receives lane J's x.
// Pure VALU (no LDS pipe). Quads are always fully active together.
template <int J>
__device__ __forceinline__ float dpp_bcast(float x) {
    constexpr int ctrl = J | (J << 2) | (J << 4) | (J << 6);  // quad_perm
    int xi = __builtin_bit_cast(int, x);
    int r  = __builtin_amdgcn_mov_dpp(xi, ctrl, 0xf, 0xf, true);
    return __builtin_bit_cast(float, r);
}

// ---------------------------------------------------------------------------
// Main kernel, v5 (= verified v4 + NONTEMPORAL INPUT LOADS, single lever):
//  v4 post-mortem: traffic clean (FETCH 66.7, WRITE 133 MB) but dur identical
//  to round 0 (82 vs 81 µs) -> prefetch depth is a null lever. The invariant
//  across ALL rounds is write drain ~1.55 TB/s (dur == WRITE_SIZE/1.55 for
//  rounds 0/3/4/5), while m13 copy writes at ~3.15 TB/s. Input(128)+output
//  (125) == L3 capacity (256 MB): writes allocate into a full LLC. nt loads
//  keep the streamed input OUT of L2/L3, freeing the LLC for write drain.
//  Dense 1KB/wave reads have no nt sector-amplification risk (that failure
//  mode was store-side write-combining bypass).
// ---------------------------------------------------------------------------
__global__ __launch_bounds__(256, 4) void scm_main(
        const float* __restrict__ eps,
        const float* __restrict__ Minv,
        const float2* __restrict__ Ctab,
        float* __restrict__ out, int B) {
    __shared__ float2 sC[16 * (N_PTS + 1)];   // 12928 B
    __shared__ float4 sM[64];                 // 1024 B; sM[k*4+q] = Minv[k][4q..4q+3]

    const int t = threadIdx.x;
    const int q = t & 3;                      // quarter within row

    for (int i = t; i < 16 * (N_PTS + 1); i += 256) sC[i] = Ctab[i];
    ((float*)sM)[t] = Minv[t];                // flat copy == desired layout
    __syncthreads();

    const float4* sMq = sM + q;               // sMq[4*k] = Minv[k][4q..4q+3]

    const int total  = B * 4;                 // float4 count (8M, fits int)
    const int stride = (int)gridDim.x * 256;
    const int sstep  = stride * 2;            // two rows per iteration
    int base = (int)blockIdx.x * 256 + t;

    const float4* in4  = (const float4*)eps;
    float4*       out4 = (float4*)out;

    const float4 zero4 = make_float4(0.f, 0.f, 0.f, 0.f);

    float4 curA = (base < total)          ? nt_load4(in4 + base)          : zero4;
    float4 curB = (base + stride < total) ? nt_load4(in4 + base + stride) : zero4;

    for (; base < total; base += sstep) {
        // prefetch next pair (2 loads in flight across this iteration's compute)
        const int nb = base + sstep;
        float4 nxtA = (nb < total)          ? nt_load4(in4 + nb)          : zero4;
        float4 nxtB = (nb + stride < total) ? nt_load4(in4 + nb + stride) : zero4;

        float4 zA = zero4;
        float4 zB = zero4;

        // k-outer: one ds_read_b128 of the Minv row-quarter per k, reused by
        // both rows; 8 independent FMA chains. e[k=4G+C] = dpp_bcast<G>(comp C).
#define SCM_STEP(G, C, COMP)                                                   \
        {                                                                      \
            const float4 mk = sMq[4 * (4 * (G) + (C))];                        \
            const float eA = dpp_bcast<(G)>(curA.COMP);                        \
            const float eB = dpp_bcast<(G)>(curB.COMP);                        \
            zA.x = fmaf(eA, mk.x, zA.x); zA.y = fmaf(eA, mk.y, zA.y);          \
            zA.z = fmaf(eA, mk.z, zA.z); zA.w = fmaf(eA, mk.w, zA.w);          \
            zB.x = fmaf(eB, mk.x, zB.x); zB.y = fmaf(eB, mk.y, zB.y);          \
            zB.z = fmaf(eB, mk.z, zB.z); zB.w = fmaf(eB, mk.w, zB.w);          \
        }
        SCM_STEP(0, 0, x) SCM_STEP(0, 1, y) SCM_STEP(0, 2, z) SCM_STEP(0, 3, w)
        SCM_STEP(1, 0, x) SCM_STEP(1, 1, y) SCM_STEP(1, 2, z) SCM_STEP(1, 3, w)
        SCM_STEP(2, 0, x) SCM_STEP(2, 1, y) SCM_STEP(2, 2, z) SCM_STEP(2, 3, w)
        SCM_STEP(3, 0, x) SCM_STEP(3, 1, y) SCM_STEP(3, 2, z) SCM_STEP(3, 3, w)
#undef SCM_STEP

        // PWL + store, row A then row B (all scalars, no arrays)
#define SCM_PWL_STORE(ZV, IDX)                                                 \
        if ((IDX) < total) {                                                   \
            float o0, o1, o2, o3;                                              \
            {                                                                  \
                const float zd = (ZV).x;                                       \
                int id = (int)floorf((zd - VMIN_F) * INV_INT_LEN_F) + 1;       \
                id = min(max(id, 0), N_PTS);                                   \
                const int spi = max(id - 1, 0);                                \
                const float sp = VMIN_F + (float)spi * INT_LEN_F;              \
                const float2 c = sC[(4 * q + 0) * (N_PTS + 1) + id];           \
                o0 = fmaf(zd - sp, c.x, c.y);                                  \
            }                                                                  \
            {                                                                  \
                const float zd = (ZV).y;                                       \
                int id = (int)floorf((zd - VMIN_F) * INV_INT_LEN_F) + 1;       \
                id = min(max(id, 0), N_PTS);                                   \
                const int spi = max(id - 1, 0);                                \
                const float sp = VMIN_F + (float)spi * INT_LEN_F;              \
                const float2 c = sC[(4 * q + 1) * (N_PTS + 1) + id];           \
                o1 = fmaf(zd - sp, c.x, c.y);                                  \
            }                                                                  \
            {                                                                  \
                const float zd = (ZV).z;                                       \
                int id = (int)floorf((zd - VMIN_F) * INV_INT_LEN_F) + 1;       \
                id = min(max(id, 0), N_PTS);                                   \
                const int spi = max(id - 1, 0);                                \
                const float sp = VMIN_F + (float)spi * INT_LEN_F;              \
                const float2 c = sC[(4 * q + 2) * (N_PTS + 1) + id];           \
                o2 = fmaf(zd - sp, c.x, c.y);                                  \
            }                                                                  \
            {                                                                  \
                const float zd = (ZV).w;                                       \
                int id = (int)floorf((zd - VMIN_F) * INV_INT_LEN_F) + 1;       \
                id = min(max(id, 0), N_PTS);                                   \
                const int spi = max(id - 1, 0);                                \
                const float sp = VMIN_F + (float)spi * INT_LEN_F;              \
                const float2 c = sC[(4 * q + 3) * (N_PTS + 1) + id];           \
                o3 = fmaf(zd - sp, c.x, c.y);                                  \
            }                                                                  \
            out4[(IDX)] = make_float4(o0, o1, o2, o3);                         \
        }

        SCM_PWL_STORE(zA, base)
        SCM_PWL_STORE(zB, base + stride)
#undef SCM_PWL_STORE

        curA = nxtA;
        curB = nxtB;
    }
}

extern "C" void kernel_launch(void* const* d_in, const int* in_sizes, int n_in,
                              void* d_out, int out_size, void* d_ws, size_t ws_size,
                              hipStream_t stream) {
    const float* eps = (const float*)d_in[0];
    const float* A   = (const float*)d_in[1];
    const float* p   = (const float*)d_in[2];
    const float* b   = (const float*)d_in[3];
    float* out = (float*)d_out;

    const int B = in_sizes[0] / D_DIM;

    // workspace layout: Minv[256 floats] | Ctab[16*101 float2] (8B-aligned)
    float*  ws   = (float*)d_ws;
    float*  Minv = ws;
    float2* Ctab = (float2*)(ws + 256);

    scm_setup<<<1, 256, 0, stream>>>(A, p, b, Minv, Ctab);

    long total_f4 = (long)B * 4;
    int blocks = (int)((total_f4 + 255) / 256);
    if (blocks > 2048) blocks = 2048;
    if (blocks < 1) blocks = 1;
    scm_main<<<blocks, 256, 0, stream>>>(eps, Minv, Ctab, out, B);
}